// Round 1
// 537.562 us; speedup vs baseline: 1.1336x; 1.1336x over previous
//
#include <hip/hip_runtime.h>

// Residual VQ, fully fused, exact-fp32 residual chain.
// Round 9: occupancy doubling. 512-thread blocks, 8 waves x ONE 16-point
// M-tile each (was 4 waves x two tiles). Same LDS (74752 B -> 2 blocks/CU),
// same grid (512), but 16 waves/CU = 4 waves/SIMD (was 8/CU = 2/SIMD).
// Per-tile math is instruction-identical to round 6/8: single 12-MFMA chain
// per tile per ng in the same kk/hi-lo order, deferred fold via X/Y ping-pong
// pending sets, ascending-cw candidate order, exact fp32 recheck of top-2.
// NEVER reorder the chain: approx-distance bits are part of the passing
// contract. lossAcc collapsed to one scalar (stages share normalization).
// N=65536 pts, D=128, S=4 stages, K=2048 codewords.
// Out (flat f32): x_q [N*D] @0, mean_loss @N*D, indices [N,S] as float @N*D+1.

#define N_PTS   65536
#define DDIM    128
#define NSTAGE  4
#define KCB     2048
#define BETA_F  0.25f

#define XQ_SIZE (N_PTS * DDIM)
#define IDX_OFF (XQ_SIZE + 1)

// ws layout (float units)
#define WS_LOSS 0                         // 4 floats
#define WS_CN   16                        // NSTAGE*KCB floats
#define WS_FRAG (16 + NSTAGE * KCB)       // frag stream, 16B-aligned
#define FRAG_S8 (32 * 32 * 64)            // short8 per stage = 65536 (1 MB)

typedef __attribute__((ext_vector_type(8))) short short8;
typedef __attribute__((ext_vector_type(4))) float f32x4;

__device__ inline short f2bf(float x) {            // RTNE bf16
    union { float f; unsigned u; } v; v.f = x;
    unsigned r = v.u + 0x7FFFu + ((v.u >> 16) & 1u);
    return (short)(r >> 16);
}
__device__ inline float bf2f(short h) {
    union { unsigned u; float f; } v; v.u = ((unsigned)(unsigned short)h) << 16;
    return v.f;
}
__device__ inline void gload_lds16(const void* g, void* l) {
    __builtin_amdgcn_global_load_lds(
        (const __attribute__((address_space(1))) unsigned int*)g,
        (__attribute__((address_space(3))) unsigned int*)l, 16, 0, 0);
}
__device__ inline void upd2(float& d1, int& i1, float& d2, int& i2, float d, int i) {
    bool lt1 = d < d1;
    bool lt2 = d < d2;
    float nd2 = lt1 ? d1 : (lt2 ? d : d2);
    int   ni2 = lt1 ? i1 : (lt2 ? i : i2);
    d1 = lt1 ? d : d1;  i1 = lt1 ? i : i1;
    d2 = nd2;           i2 = ni2;
}

// ||c||^2 per codeword + zero loss accumulators
__global__ void cnorm_init(const float* __restrict__ cb, float* __restrict__ ws) {
    int t = blockIdx.x * blockDim.x + threadIdx.x;   // 131072 threads
    int row = t >> 4;                                // 0..8191 (s*K + k)
    int q   = t & 15;
    const float4* rp = (const float4*)(cb + (size_t)row * DDIM);
    float s = 0.f;
    #pragma unroll
    for (int j = 0; j < 2; ++j) {
        float4 v = rp[q * 2 + j];
        s += v.x * v.x + v.y * v.y + v.z * v.z + v.w * v.w;
    }
    #pragma unroll
    for (int m = 1; m < 16; m <<= 1) s += __shfl_xor(s, m);
    if (q == 0) ws[WS_CN + row] = s;
    if (t < 4) ws[WS_LOSS + t] = 0.f;
}

// Pack codebook into MFMA-B-frag-linear bf16 hi/lo layout:
// id = (((s*32 + c)*4 + nt)*4 + kk)*2*64 + h*64 + lane ; 16 B per id.
// lane's 8 bf16 = cb[s][c*64 + nt*16 + (lane&15)][kk*32 + (lane>>4)*8 .. +8]
__global__ void frag_pack(const float* __restrict__ cb, float* __restrict__ ws) {
    int id   = blockIdx.x * 256 + threadIdx.x;       // 0..262143
    int lane = id & 63;
    int h    = (id >> 6) & 1;
    int kk   = (id >> 7) & 3;
    int nt   = (id >> 9) & 3;
    int c    = (id >> 11) & 31;
    int s    = (id >> 16);
    int row  = c * 64 + nt * 16 + (lane & 15);
    int koff = kk * 32 + (lane >> 4) * 8;
    const float* src = cb + ((size_t)(s * KCB + row) * DDIM + koff);
    short8 v;
    #pragma unroll
    for (int j = 0; j < 8; ++j) {
        float xv = src[j];
        short hi = f2bf(xv);
        if (h) { v[j] = f2bf(xv - bf2f(hi)); }
        else   { v[j] = hi; }
    }
    ((short8*)(ws + WS_FRAG))[id] = v;
}

#define MFMA16(A, B, C) __builtin_amdgcn_mfma_f32_16x16x32_bf16(A, B, C, 0, 0, 0)

__global__ __launch_bounds__(512, 4)
void rvq_fused(const float* __restrict__ x, const float* __restrict__ cb,
               float* __restrict__ ws, float* __restrict__ out) {
    __shared__ short8 Bbuf[2][2048];                 // 2 x 32 KB
    __shared__ float  sCn[KCB];                      // 8 KB, per-stage ||c||^2
    __shared__ int    sC1[128], sC2[128];

    const int t    = threadIdx.x;
    const int lane = t & 63;
    const int w    = t >> 6;                         // wave 0..7
    const int m    = lane & 15;
    const int q    = lane >> 4;
    const size_t pt = (size_t)blockIdx.x * 128 + w * 16 + m;  // wave's 16 pts

    const short8* fragAll = (const short8*)(ws + WS_FRAG);

    // Exact fp32 residual R + split-bf16 A-frags, one M-tile per wave.
    // A[m][k]: row m = point pt, k = kk*32 + q*8 + j.
    float  R[4][8];
    short8 Ahi[4], Alo[4];
    #pragma unroll
    for (int kk = 0; kk < 4; ++kk) {
        const float* rp = x + pt * DDIM + kk * 32 + q * 8;
        float4 v0 = *(const float4*)rp;
        float4 v1 = *(const float4*)(rp + 4);
        R[kk][0] = v0.x; R[kk][1] = v0.y;
        R[kk][2] = v0.z; R[kk][3] = v0.w;
        R[kk][4] = v1.x; R[kk][5] = v1.y;
        R[kk][6] = v1.z; R[kk][7] = v1.w;
        short8 hi8, lo8;
        #pragma unroll
        for (int j = 0; j < 8; ++j) {
            short hi = f2bf(R[kk][j]);
            hi8[j] = hi;
            lo8[j] = f2bf(R[kk][j] - bf2f(hi));
        }
        Ahi[kk] = hi8; Alo[kk] = lo8;
    }

    float lossAcc = 0.f;   // stages share normalization -> single accumulator

    // prefetch stage 0 chunk 0 + stage 0 cn
    #pragma unroll
    for (int j = 0; j < 4; ++j) {
        int idx = t + j * 512;
        gload_lds16(fragAll + idx, &Bbuf[0][idx]);
    }
    gload_lds16(ws + WS_CN + 4 * t, &sCn[4 * t]);    // 512 x 16B = 8 KB

    #pragma unroll 1
    for (int s = 0; s < NSTAGE; ++s) {
        const short8* frag = fragAll + (size_t)s * FRAG_S8;
        const float*  cbs  = cb + (size_t)s * KCB * DDIM;

        float d1[4], d2[4]; int i1[4], i2[4];
        #pragma unroll
        for (int r = 0; r < 4; ++r) {
            d1[r] = 3e38f; d2[r] = 3e38f;
            i1[r] = 0;     i2[r] = 1;
        }

        // Deferred-fold pending acc sets (distinct registers -> no WAR with
        // the next chain). Y starts fake: dist = +6e37, evicted by the first
        // two real candidates; cwp=0. Fold values bitwise-identical to
        // round 6 (same chain, same fmaf, same ascending cw order).
        const f32x4 fake = {-3e37f, -3e37f, -3e37f, -3e37f};
        f32x4 Xa = fake, Ya = fake;
        int cwp = 0;

        #pragma unroll 1
        for (int c = 0; c < 32; ++c) {
            __syncthreads();                 // buf[c&1] + sCn resident
            if (c + 1 < 32) {
                const short8* src = frag + (size_t)(c + 1) * 2048;
                #pragma unroll
                for (int j = 0; j < 4; ++j) {
                    int idx = t + j * 512;
                    gload_lds16(src + idx, &Bbuf[(c + 1) & 1][idx]);
                }
            } else if (s + 1 < NSTAGE) {     // cross-stage prefetch into buf0
                const short8* src = frag + FRAG_S8;
                #pragma unroll
                for (int j = 0; j < 4; ++j) {
                    int idx = t + j * 512;
                    gload_lds16(src + idx, &Bbuf[0][idx]);
                }
            }
            const short8* B = Bbuf[c & 1];
            #pragma unroll
            for (int ng = 0; ng < 4; ++ng) {
                // ---- fold pending (deferred one ng; other parity set)
                {
                    float cnv = sCn[cwp];
                    if ((ng & 1) == 0) {
                        #pragma unroll
                        for (int r = 0; r < 4; ++r) {
                            float dt = fmaf(-2.f, Ya[r], cnv);
                            upd2(d1[r], i1[r], d2[r], i2[r], dt, cwp);
                        }
                    } else {
                        #pragma unroll
                        for (int r = 0; r < 4; ++r) {
                            float dt = fmaf(-2.f, Xa[r], cnv);
                            upd2(d1[r], i1[r], d2[r], i2[r], dt, cwp);
                        }
                    }
                }
                // ---- chain ng: round-6 bitwise order (single chain per tile)
                f32x4 ca = {0.f, 0.f, 0.f, 0.f};
                #pragma unroll
                for (int kk = 0; kk < 4; ++kk) {
                    short8 bh = B[((ng * 4 + kk) * 2 + 0) * 64 + lane];
                    short8 bl = B[((ng * 4 + kk) * 2 + 1) * 64 + lane];
                    ca = MFMA16(Ahi[kk], bh, ca);
                    ca = MFMA16(Alo[kk], bh, ca);
                    ca = MFMA16(Ahi[kk], bl, ca);
                }
                // ---- stash as pending
                if ((ng & 1) == 0) { Xa = ca; }
                else               { Ya = ca; }
                cwp = c * 64 + ng * 16 + m;
            }
        }
        // final pending fold (set Y, from c=31 ng=3)
        {
            float cnv = sCn[cwp];
            #pragma unroll
            for (int r = 0; r < 4; ++r) {
                float dt = fmaf(-2.f, Ya[r], cnv);
                upd2(d1[r], i1[r], d2[r], i2[r], dt, cwp);
            }
        }

        // merge top-2 across the 16 codeword columns (m lanes)
        #pragma unroll
        for (int mm = 1; mm < 16; mm <<= 1) {
            #pragma unroll
            for (int r = 0; r < 4; ++r) {
                float od1 = __shfl_xor(d1[r], mm); int oi1 = __shfl_xor(i1[r], mm);
                float od2 = __shfl_xor(d2[r], mm); int oi2 = __shfl_xor(i2[r], mm);
                upd2(d1[r], i1[r], d2[r], i2[r], od1, oi1);
                upd2(d1[r], i1[r], d2[r], i2[r], od2, oi2);
            }
        }
        if (m == 0) {                        // redistribute: D rows -> A rows
            #pragma unroll
            for (int r = 0; r < 4; ++r)
                { sC1[w * 16 + q * 4 + r] = i1[r];
                  sC2[w * 16 + q * 4 + r] = i2[r]; }
        }
        __syncthreads();

        {
            int ia = sC1[w * 16 + m];
            int ib = sC2[w * 16 + m];

            // exact fp32 recheck against R: lane covers k = kk*32 + q*8 .. +8
            float pa = 0.f, pb = 0.f, pr = 0.f;
            #pragma unroll
            for (int kk = 0; kk < 4; ++kk) {
                const float* pav = cbs + (size_t)ia * DDIM + kk * 32 + q * 8;
                const float* pbv = cbs + (size_t)ib * DDIM + kk * 32 + q * 8;
                float4 a0 = *(const float4*)pav, a1 = *(const float4*)(pav + 4);
                float4 b0 = *(const float4*)pbv, b1 = *(const float4*)(pbv + 4);
                float av[8] = {a0.x, a0.y, a0.z, a0.w, a1.x, a1.y, a1.z, a1.w};
                float bv[8] = {b0.x, b0.y, b0.z, b0.w, b1.x, b1.y, b1.z, b1.w};
                #pragma unroll
                for (int j = 0; j < 8; ++j) {
                    float rv = R[kk][j];
                    pa += rv * av[j];
                    pb += rv * bv[j];
                    pr += rv * rv;
                }
            }
            pa += __shfl_xor(pa, 16); pa += __shfl_xor(pa, 32);
            pb += __shfl_xor(pb, 16); pb += __shfl_xor(pb, 32);
            pr += __shfl_xor(pr, 16); pr += __shfl_xor(pr, 32);
            float dA = sCn[ia] - 2.f * pa;
            float dB = sCn[ib] - 2.f * pb;
            bool bw = (dB < dA) || (dB == dA && ib < ia);   // first-occurrence
            int  wi = bw ? ib : ia;
            if (q == 0) {
                out[IDX_OFF + pt * NSTAGE + s] = (float)wi;
                lossAcc += (bw ? dB : dA) + pr;             // ||c - r||^2
            }

            // exact update: R -= c_win; re-split frags; last stage: x_q = x - R
            const float* cwr = cbs + (size_t)wi * DDIM;
            #pragma unroll
            for (int kk = 0; kk < 4; ++kk) {
                const float* pwv = cwr + kk * 32 + q * 8;
                float4 w0 = *(const float4*)pwv, w1 = *(const float4*)(pwv + 4);
                float wv[8] = {w0.x, w0.y, w0.z, w0.w, w1.x, w1.y, w1.z, w1.w};
                short8 hi8, lo8;
                #pragma unroll
                for (int j = 0; j < 8; ++j) {
                    float v = R[kk][j] - wv[j];
                    R[kk][j] = v;
                    short hi = f2bf(v);
                    hi8[j] = hi;
                    lo8[j] = f2bf(v - bf2f(hi));
                }
                Ahi[kk] = hi8; Alo[kk] = lo8;
                if (s == NSTAGE - 1) {
                    const float* xp = x + pt * DDIM + kk * 32 + q * 8;
                    float4 x0 = *(const float4*)xp, x1 = *(const float4*)(xp + 4);
                    float* op = out + pt * DDIM + kk * 32 + q * 8;
                    *(float4*)op = make_float4(x0.x - R[kk][0], x0.y - R[kk][1],
                                               x0.z - R[kk][2], x0.w - R[kk][3]);
                    *(float4*)(op + 4) = make_float4(x1.x - R[kk][4], x1.y - R[kk][5],
                                                     x1.z - R[kk][6], x1.w - R[kk][7]);
                }
            }
        }

        // stage-end barrier: recheck reads of sCn/sC done before next-stage
        // sCn overwrite and Bbuf reuse
        __syncthreads();
        if (s + 1 < NSTAGE) {                // stage s+1 cn -> LDS
            const float* cnn = ws + WS_CN + (s + 1) * KCB;
            gload_lds16(cnn + 4 * t, &sCn[4 * t]);
        }
    }

    // loss: wave reduce, one atomic per wave
    #pragma unroll
    for (int mm = 1; mm < 64; mm <<= 1)
        lossAcc += __shfl_xor(lossAcc, mm);
    if (lane == 0)
        atomicAdd(ws + WS_LOSS, lossAcc);
}

__global__ void rvq_finalize(const float* __restrict__ ws, float* __restrict__ out) {
    float sum = ws[0] + ws[1] + ws[2] + ws[3];
    out[XQ_SIZE] = (1.f + BETA_F) * sum /
                   ((float)NSTAGE * (float)N_PTS * (float)DDIM);
}

extern "C" void kernel_launch(void* const* d_in, const int* in_sizes, int n_in,
                              void* d_out, int out_size, void* d_ws, size_t ws_size,
                              hipStream_t stream) {
    const float* x  = (const float*)d_in[0];
    const float* cb = (const float*)d_in[1];
    float* out = (float*)d_out;
    float* ws  = (float*)d_ws;

    cnorm_init<<<512, 256, 0, stream>>>(cb, ws);
    frag_pack<<<1024, 256, 0, stream>>>(cb, ws);
    rvq_fused<<<512, 512, 0, stream>>>(x, cb, ws, out);
    rvq_finalize<<<1, 1, 0, stream>>>(ws, out);
}